// Round 1
// baseline (315.483 us; speedup 1.0000x reference)
//
#include <hip/hip_runtime.h>
#include <cstdint>

#define BB 64
#define SS 2048

typedef float f32x4 __attribute__((ext_vector_type(4)));

// ---------------------------------------------------------------------------
// Fused prep kernel, 368 blocks x 256 threads:
//   blocks [0,256)   : P = pos @ W[0:512]     (2048x512 f32 GEMM, 64x64 tiles,
//                      register-prefetch double-buffered LDS staging)
//   blocks [256,304) : NG[24][512] = {nest @ W[512:1024] ; seg @ W[1024:1536]}
//                      (trivial dot kernel, 1 output/thread)
//   blocks [304,368) : per-row syntax scan -> idx = nest*8 + seg
// NOTE: accumulation order is strictly sequential in k everywhere (absmax==0).
// ---------------------------------------------------------------------------
__global__ __launch_bounds__(256) void prep_kernel(
    const int* __restrict__ tok, const float* __restrict__ pos,
    const float* __restrict__ nest, const float* __restrict__ seg,
    const float* __restrict__ W,
    int* __restrict__ idx, float* __restrict__ P, float* __restrict__ NG) {
    const int blk = blockIdx.x;
    const int tid = threadIdx.x;

    if (blk < 256) {
        // ---- P GEMM: 64x64 tile, 4x4 micro, K-tile 16 ----
        __shared__ float As[16][68];   // [k][m], pad 68: staging writes 2-way,
                                       // row stride 272B = 16-aligned for b128 reads
        __shared__ float Bs[16][64];   // [k][n]
        const int bm = (blk >> 3) << 6;     // 32 m-tiles
        const int bn = (blk & 7) << 6;      // 8 n-tiles
        const int am = tid >> 2, ak = (tid & 3) << 2;   // A staging coords
        const int bk = tid >> 4, bn2 = (tid & 15) << 2; // B staging coords
        const int tn = tid & 15, tm = tid >> 4;         // micro-tile coords

        const float* Ap = pos + (size_t)(bm + am) * 512 + ak;
        const float* Bp = W + (size_t)bk * 512 + bn + bn2;
        float4 aR = *(const float4*)Ap;
        float4 bR = *(const float4*)Bp;

        float acc[4][4];
#pragma unroll
        for (int i = 0; i < 4; ++i)
#pragma unroll
            for (int j = 0; j < 4; ++j) acc[i][j] = 0.0f;

        for (int k0 = 0; k0 < 512; k0 += 16) {
            __syncthreads();
            As[ak + 0][am] = aR.x; As[ak + 1][am] = aR.y;
            As[ak + 2][am] = aR.z; As[ak + 3][am] = aR.w;
            *(float4*)&Bs[bk][bn2] = bR;
            __syncthreads();
            if (k0 + 16 < 512) {   // prefetch next tile; overlaps compute below
                aR = *(const float4*)(Ap + k0 + 16);
                bR = *(const float4*)(Bp + (size_t)(k0 + 16) * 512);
            }
#pragma unroll
            for (int kk = 0; kk < 16; ++kk) {
                float4 a = *(const float4*)&As[kk][tm << 2];
                float4 b = *(const float4*)&Bs[kk][tn << 2];
                float av[4] = {a.x, a.y, a.z, a.w};
                float bv[4] = {b.x, b.y, b.z, b.w};
#pragma unroll
                for (int i = 0; i < 4; ++i)
#pragma unroll
                    for (int j = 0; j < 4; ++j) acc[i][j] += av[i] * bv[j];
            }
        }
#pragma unroll
        for (int i = 0; i < 4; ++i) {
            float4 o = make_float4(acc[i][0], acc[i][1], acc[i][2], acc[i][3]);
            *(float4*)(P + (size_t)(bm + (tm << 2) + i) * 512 + bn + (tn << 2)) = o;
        }
    } else if (blk < 304) {
        // ---- NG dot kernel: rows 0..15 = nest@W1, rows 16..23 = seg@W2 ----
        const int b2 = blk - 256;
        const int row = b2 >> 1;
        const int col = ((b2 & 1) << 8) + tid;
        const float* Ta = (row < 16) ? (nest + (size_t)row * 512)
                                     : (seg + (size_t)(row - 16) * 512);
        const float* Wx = W + ((row < 16) ? (size_t)512 * 512 : (size_t)1024 * 512);
        float s = 0.0f;
#pragma unroll 8
        for (int k = 0; k < 512; ++k) s += Ta[k] * Wx[(size_t)k * 512 + col];
        NG[(size_t)row * 512 + col] = s;
    } else {
        // ---- syntax scan: one block per batch row ----
        __shared__ int sS[256], sM[256], sG[256];
        const int b = blk - 304;
        const int* t = tok + (size_t)b * SS;
        int4 w0 = reinterpret_cast<const int4*>(t)[tid * 2 + 0];
        int4 w1 = reinterpret_cast<const int4*>(t)[tid * 2 + 1];
        int tk[8] = {w0.x, w0.y, w0.z, w0.w, w1.x, w1.y, w1.z, w1.w};

        int ls[8], lmin[8], lseg[8];
        int s = 0, m = 2147483647, sg = 0;
#pragma unroll
        for (int j = 0; j < 8; ++j) {
            int v = tk[j];
            int open_ = (v == 40) | (v == 123) | (v == 91);
            int close_ = (v == 41) | (v == 125) | (v == 93);
            s += open_ - close_;
            m = min(m, s);
            sg += (v > 39990) ? 1 : 0;
            ls[j] = s; lmin[j] = m; lseg[j] = sg;
        }
        sS[tid] = s; sM[tid] = m; sG[tid] = sg;
        __syncthreads();
        for (int off = 1; off < 256; off <<= 1) {
            int aS = 0, aM = 2147483647, aG = 0;
            bool has = (tid >= off);
            if (has) { aS = sS[tid - off]; aM = sM[tid - off]; aG = sG[tid - off]; }
            __syncthreads();
            if (has) {
                sM[tid] = min(aM, aS + sM[tid]);
                sS[tid] = aS + sS[tid];
                sG[tid] = aG + sG[tid];
            }
            __syncthreads();
        }
        int pS = 0, pM = 2147483647, pG = 0;
        if (tid > 0) { pS = sS[tid - 1]; pM = sM[tid - 1]; pG = sG[tid - 1]; }

        int res[8];
#pragma unroll
        for (int j = 0; j < 8; ++j) {
            int gs = pS + ls[j];
            int rm = min(pM, pS + lmin[j]);
            int nst = gs - min(rm, 0);
            nst = max(0, min(15, nst));
            int sgm = (pG + lseg[j]) & 7;
            res[j] = nst * 8 + sgm;
        }
        int4* op = reinterpret_cast<int4*>(idx + (size_t)b * SS + tid * 8);
        op[0] = make_int4(res[0], res[1], res[2], res[3]);
        op[1] = make_int4(res[4], res[5], res[6], res[7]);
    }
}

// ---------------------------------------------------------------------------
// Output kernel v2: out[b,s,:] = P[s,:] + NG[nest,:] + NG[16+seg,:]
// 2048 blocks = one per s (XCD-bijective swizzle: each XCD owns a contiguous
// 256-s range -> idx cache lines and P rows fetched once per XCD, not 8x).
// 256 threads = 2 b-rows x 128 float4 cols; loop 32x over b -> 64 rows/block.
// idx column staged in LDS once per block (no dependent global load in the
// store loop). Output written with nontemporal stores (write-once 256 MiB
// stream should not allocate in L2/L3).
// Exactly 8 blocks/CU at 4 waves -> 32 waves/CU full occupancy.
// ---------------------------------------------------------------------------
__global__ __launch_bounds__(256) void out_kernel(const f32x4* __restrict__ P,
                                                  const f32x4* __restrict__ NG,
                                                  const int* __restrict__ idx,
                                                  f32x4* __restrict__ out) {
    __shared__ int sIdx[64];
    const int bid = blockIdx.x;
    const int s = ((bid & 7) << 8) + (bid >> 3);   // XCD-contiguous s ranges
    const int tx = threadIdx.x & 127;
    const int tz = threadIdx.x >> 7;

    if (threadIdx.x < 64) sIdx[threadIdx.x] = idx[(size_t)threadIdx.x * SS + s];
    const f32x4 p = P[(size_t)s * 128 + tx];
    __syncthreads();

#pragma unroll 4
    for (int i = 0; i < 32; ++i) {
        const int b = (i << 1) + tz;
        const int id = sIdx[b];
        const f32x4 nv = NG[(size_t)(id >> 3) * 128 + tx];
        const f32x4 gv = NG[(size_t)(16 + (id & 7)) * 128 + tx];
        f32x4 o = (p + nv) + gv;   // same add order as before: absmax stays 0
        __builtin_nontemporal_store(o, &out[((size_t)b * SS + s) * 128 + tx]);
    }
}

// ---------------------------------------------------------------------------
extern "C" void kernel_launch(void* const* d_in, const int* in_sizes, int n_in,
                              void* d_out, int out_size, void* d_ws, size_t ws_size,
                              hipStream_t stream) {
    const int* tok = (const int*)d_in[0];      // [64,2048] int32
    const float* pos = (const float*)d_in[1];  // [2048,512]
    const float* nest = (const float*)d_in[2]; // [16,512]
    const float* seg = (const float*)d_in[3];  // [8,512]
    const float* W = (const float*)d_in[4];    // [1536,512]
    float* out = (float*)d_out;                // [64,2048,512]

    char* ws = (char*)d_ws;
    int* idx = (int*)ws;                               // 512 KB
    float* P = (float*)(ws + (512 << 10));             // 4 MB
    float* NG = (float*)(ws + (512 << 10) + (4 << 20)); // 48 KB

    prep_kernel<<<368, 256, 0, stream>>>(tok, pos, nest, seg, W, idx, P, NG);
    out_kernel<<<2048, 256, 0, stream>>>(
        (const f32x4*)P, (const f32x4*)NG, idx, (f32x4*)out);
}